// Round 12
// baseline (163.319 us; speedup 1.0000x reference)
//
#include <hip/hip_runtime.h>
#include <hip/hip_bf16.h>
#include <stdint.h>

typedef unsigned long long u64;
typedef unsigned int u32;
typedef unsigned short u16;

#define NANCH 10647
#define NBATCH 16
#define NSORT 16384
#define NSEL 2048
#define NWORD 32
#define NCLS 80
#define CONF_T 0.5f
#define NMS_T 0.5f
#define MAXDET 300
#define MAXWH 4096.0f
#define CANDCAP 10688   // >= NANCH, 64-aligned

// ---------------- Kernel 0: zero ghist + gkeep ----------------
__global__ __launch_bounds__(1024) void k_zero(u32* __restrict__ p, int nwords) {
    for (int i = threadIdx.x; i < nwords; i += 1024) p[i] = 0;
}

// ---------------- Kernel 1: per-anchor prep (+ top-byte histogram) ----------------
__global__ __launch_bounds__(256) void k_prep(const float* __restrict__ pred,
                                              u64* __restrict__ keys,
                                              float4* __restrict__ boxes,
                                              int* __restrict__ cls,
                                              float* __restrict__ score,
                                              u32* __restrict__ ghist) {
    __shared__ float sm[128 * 85];
    __shared__ u32 ph[256];
    int b = blockIdx.y;
    int a0 = blockIdx.x * 128;
    int na = NANCH - a0; if (na > 128) na = 128;
    const float* src = pred + ((size_t)b * NANCH + a0) * 85;
    int tot = na * 85;
    ph[threadIdx.x] = 0;
    for (int i = threadIdx.x; i < tot; i += 256) sm[i] = src[i];
    __syncthreads();
    int t = threadIdx.x;
    u64 kk = 0;
    if (t < na) {
        const float* s = &sm[t * 85];
        float x = s[0], y = s[1], w = s[2], h = s[3], obj = s[4];
        float best = s[5] * obj; int arg = 0;
        #pragma unroll
        for (int c = 1; c < 80; ++c) {
            float v = s[5 + c] * obj;
            if (v > best) { best = v; arg = c; }
        }
        bool valid = obj >= CONF_T;
        float sc = valid ? best : -1.0f;
        int a = a0 + t;
        float4 bx;
        bx.x = x - w * 0.5f; bx.y = y - h * 0.5f;
        bx.z = x + w * 0.5f; bx.w = y + h * 0.5f;
        size_t o = (size_t)b * NANCH + a;
        boxes[o] = bx;
        cls[o] = arg;
        score[o] = sc;
        u32 u = __float_as_uint(sc);
        u32 v = (u & 0x80000000u) ? ~u : (u | 0x80000000u); // ascending map
        u32 hi = ~v;                                        // descending
        kk = ((u64)hi << 32) | (u32)a;
        keys[(size_t)b * NSORT + a] = kk;
    }
    // wave-aggregated 256-bin histogram of key top byte
    u32 bin = (t < na) ? (u32)(kk >> 56) : 0xFFFFFFFFu;
    int lane = t & 63;
    u64 rem = __ballot(t < na);
    while (rem) {
        int srcl = __ffsll((long long)rem) - 1;
        u32 lb = __shfl(bin, srcl);
        u64 same = __ballot(bin == lb) & rem;
        if (lane == srcl) atomicAdd(&ph[lb], (u32)__popcll(same));
        rem &= ~same;
    }
    __syncthreads();
    if (ph[threadIdx.x]) atomicAdd(&ghist[(size_t)b * 256 + threadIdx.x], ph[threadIdx.x]);
}

// ------- Kernel 2: histogram-seeded select + rank-scatter gather -------
// Invariant through selection: s_cnt + s_rank == NSEL at every loop entry.
__global__ __launch_bounds__(1024) void k_sel(const u64* __restrict__ keys,
                                              const u32* __restrict__ ghist,
                                              const float4* __restrict__ boxes,
                                              const int* __restrict__ cls,
                                              const float* __restrict__ score,
                                              float4* __restrict__ sel_box,
                                              float4* __restrict__ sel_sbox,
                                              float* __restrict__ sel_area,
                                              float* __restrict__ sel_score,
                                              int* __restrict__ sel_cls) {
    __shared__ u64 sk[NSEL];        // 16 KB (unsorted selected keys)
    __shared__ u64 cand[CANDCAP];   // 85.5 KB
    __shared__ u32 hist[256];
    __shared__ u32 hsc[256];
    __shared__ u64 s_red[16];
    __shared__ u32 s_D0, s_D, s_rank, s_cnt, s_cand;

    int b = blockIdx.x;
    int tid = threadIdx.x;
    int lane = tid & 63;
    u64 below = (1ULL << lane) - 1ULL;
    const u64* KB = keys + (size_t)b * NSORT;

    if (tid == 0) { s_cnt = 0; s_cand = 0; }
    for (int i = tid; i < NSEL; i += 1024) sk[i] = ~0ULL;   // safety fill
    // ---- round 0: digit from precomputed histogram ----
    if (tid < 256) hist[tid] = ghist[(size_t)b * 256 + tid];
    __syncthreads();
    if (tid < 64) {
        u32 h0 = hist[tid*4], h1 = hist[tid*4+1], h2 = hist[tid*4+2], h3 = hist[tid*4+3];
        u32 loc = h0 + h1 + h2 + h3;
        u32 p = loc;
        #pragma unroll
        for (int o = 1; o < 64; o <<= 1) { u32 t2 = __shfl_up(p, o); if (lane >= o) p += t2; }
        u32 base = p - loc;
        hsc[tid*4]   = base + h0;
        hsc[tid*4+1] = base + h0 + h1;
        hsc[tid*4+2] = base + h0 + h1 + h2;
        hsc[tid*4+3] = base + h0 + h1 + h2 + h3;
    }
    __syncthreads();
    if (tid < 256) {
        u32 inc = hsc[tid], cb = inc - hist[tid];
        if (cb < NSEL && NSEL <= inc) { s_D0 = tid; s_rank = NSEL - cb; }
    }
    __syncthreads();
    u32 D0 = s_D0;

    // ---- single fused scan: sure-set -> sk, boundary bucket -> cand ----
    for (int it = 0; it < 11; ++it) {
        int i = tid + it * 1024;
        bool inb = i < NANCH;
        u64 kk = inb ? KB[i] : 0ULL;
        u32 top = (u32)(kk >> 56);
        bool is_s = inb && (top < D0);
        bool is_c = inb && (top == D0);
        u64 bs = __ballot(is_s), bc = __ballot(is_c);
        u32 base_s = 0, base_c = 0;
        if (lane == 0) {
            if (bs) base_s = atomicAdd(&s_cnt, (u32)__popcll(bs));
            if (bc) base_c = atomicAdd(&s_cand, (u32)__popcll(bc));
        }
        base_s = __shfl(base_s, 0); base_c = __shfl(base_c, 0);
        if (is_s) sk[base_s + __popcll(bs & below)] = kk;
        if (is_c) cand[base_c + __popcll(bc & below)] = kk;
    }
    __syncthreads();

    // ---- refine within cand; append sure-members to sk each round ----
    const int shifts2[5] = {48, 40, 32, 8, 0};
    for (int rr = 0; ; ++rr) {
        u32 cn = s_cand, r = s_rank;
        if (r == cn || rr == 5) {
            for (u32 i0 = 0; i0 < cn; i0 += 1024) {
                u32 i = i0 + tid;
                bool take = i < cn;
                u64 kk = take ? cand[i] : 0ULL;
                u64 bt = __ballot(take);
                u32 base = 0;
                if (lane == 0 && bt) base = atomicAdd(&s_cnt, (u32)__popcll(bt));
                base = __shfl(base, 0);
                if (take) sk[base + __popcll(bt & below)] = kk;
            }
            break;
        }
        if (r == 1) {
            u64 best = ~0ULL;
            for (u32 i = tid; i < cn; i += 1024) { u64 kk = cand[i]; if (kk < best) best = kk; }
            #pragma unroll
            for (int o = 32; o > 0; o >>= 1) {
                u64 other = __shfl_down(best, o);
                if (other < best) best = other;
            }
            if (lane == 0) s_red[tid >> 6] = best;
            __syncthreads();
            if (tid == 0) {
                u64 m = s_red[0];
                for (int w2 = 1; w2 < 16; ++w2) if (s_red[w2] < m) m = s_red[w2];
                sk[atomicAdd(&s_cnt, 1u)] = m;
            }
            break;
        }
        int shift = shifts2[rr];
        if (tid < 256) hist[tid] = 0;
        __syncthreads();
        for (u32 i = tid; i < cn; i += 1024)
            atomicAdd(&hist[(u32)(cand[i] >> shift) & 0xFFu], 1u);
        __syncthreads();
        if (tid < 64) {
            u32 h0 = hist[tid*4], h1 = hist[tid*4+1], h2 = hist[tid*4+2], h3 = hist[tid*4+3];
            u32 loc = h0 + h1 + h2 + h3;
            u32 p = loc;
            #pragma unroll
            for (int o = 1; o < 64; o <<= 1) { u32 t2 = __shfl_up(p, o); if (lane >= o) p += t2; }
            u32 base = p - loc;
            hsc[tid*4]   = base + h0;
            hsc[tid*4+1] = base + h0 + h1;
            hsc[tid*4+2] = base + h0 + h1 + h2;
            hsc[tid*4+3] = base + h0 + h1 + h2 + h3;
        }
        __syncthreads();
        if (tid < 256) {
            u32 inc = hsc[tid], cb = inc - hist[tid];
            if (cb < r && r <= inc) { s_D = tid; s_rank = r - cb; }
        }
        __syncthreads();
        u32 D = s_D;
        // partition: digit<D -> sk (sure members), digit==D -> cand, else drop
        u64 mk[11], mc[11]; int nk = 0, nc = 0;
        for (u32 i = tid; i < cn; i += 1024) {
            u64 kk = cand[i];
            u32 dg = (u32)(kk >> shift) & 0xFFu;
            if (dg < D) mk[nk++] = kk;
            else if (dg == D) mc[nc++] = kk;
        }
        __syncthreads();
        if (tid == 0) s_cand = 0;
        __syncthreads();
        if (nk) { u32 p = atomicAdd(&s_cnt, (u32)nk); for (int j = 0; j < nk; ++j) sk[p + j] = mk[j]; }
        if (nc) { u32 p = atomicAdd(&s_cand, (u32)nc); for (int j = 0; j < nc; ++j) cand[p + j] = mc[j]; }
        __syncthreads();
    }
    __syncthreads();

    // ---- rank-scatter: position = #{keys smaller} (keys unique) ----
    // Ascending u64 key order == score desc, index asc (stable argsort order).
    u64 my0 = sk[tid], my1 = sk[tid + 1024];
    int r0 = 0, r1 = 0;
    const ulonglong2* sk2 = (const ulonglong2*)sk;
    #pragma unroll 8
    for (int j = 0; j < NSEL / 2; ++j) {
        ulonglong2 p = sk2[j];              // wave-broadcast LDS read
        r0 += (p.x < my0) + (p.y < my0);
        r1 += (p.x < my1) + (p.y < my1);
    }
    // fused gather: write each key's entry directly at its rank
    #pragma unroll
    for (int e = 0; e < 2; ++e) {
        u64 key = e ? my1 : my0;
        int rk  = e ? r1 : r0;
        int a = (int)(key & 0xFFFFFFFFu);
        if ((unsigned)a >= NANCH) a = 0;   // should never trigger
        size_t src = (size_t)b * NANCH + a;
        float4 bx = boxes[src];
        int c = cls[src];
        float sc = score[src];
        float off = (float)c * MAXWH;
        float4 sb;
        sb.x = bx.x + off; sb.y = bx.y + off;
        sb.z = bx.z + off; sb.w = bx.w + off;
        float area = (sb.z - sb.x) * (sb.w - sb.y);
        size_t o = (size_t)b * NSEL + rk;
        sel_box[o] = bx; sel_sbox[o] = sb; sel_area[o] = area;
        sel_score[o] = sc; sel_cls[o] = c;
    }
}

// ---- Kernel 3: per-class NMS (IoU matrix is block-diagonal by class) ----
__global__ __launch_bounds__(1024) void k_cnms(const float4* __restrict__ sel_sbox,
                                               const float* __restrict__ sel_area,
                                               const int* __restrict__ sel_cls,
                                               const float* __restrict__ sel_score,
                                               u64* __restrict__ gkeep) {
    __shared__ u16 wmem[16][NSEL];    // 64 KB: per-wave member list
    __shared__ u64 wkeep[16][NWORD];  // 4 KB: per-wave kept bits

    int b = blockIdx.y;
    int cg = blockIdx.x;              // class group 0..4
    int lane = threadIdx.x & 63, wv = threadIdx.x >> 6;
    int c = cg * 16 + wv;             // this wave's class, 0..79
    size_t bb = (size_t)b * NSEL;
    const int* CL = sel_cls + bb;
    const float* SC = sel_score + bb;
    u64 below = (1ULL << lane) - 1ULL;

    // ---- build member list (ascending selected index == descending score) ----
    int n = 0;
    for (int ch = 0; ch < NWORD; ++ch) {
        int i = ch * 64 + lane;
        bool pred = (CL[i] == c) && (SC[i] >= 0.0f);
        u64 bal = __ballot(pred);
        if (pred) wmem[wv][n + __popcll(bal & below)] = (u16)i;
        n += __popcll(bal);
    }

    // ---- greedy NMS over this class's members, 64 at a time ----
    for (int c0 = 0; c0 < n; c0 += 64) {
        int chunkn = n - c0; if (chunkn > 64) chunkn = 64;
        bool mv = lane < chunkn;
        int q = mv ? (int)wmem[wv][c0 + lane] : 0;
        float4 bq = sel_sbox[bb + q];
        float aq = sel_area[bb + q];

        // hit-test vs earlier kept members (only runs when n > 64)
        bool hit = false;
        for (int j = 0; j < c0; ++j) {
            if (!((wkeep[wv][j >> 6] >> (j & 63)) & 1ULL)) continue;
            int p = (int)wmem[wv][j];
            float4 bp = sel_sbox[bb + p];
            float ap = sel_area[bb + p];
            float ltx = fmaxf(bp.x, bq.x), lty = fmaxf(bp.y, bq.y);
            float rbx = fminf(bp.z, bq.z), rby = fminf(bp.w, bq.w);
            float ww = fmaxf(rbx - ltx, 0.0f), hh = fmaxf(rby - lty, 0.0f);
            float inter = ww * hh;
            hit = hit || (mv && (inter / (ap + aq - inter + 1e-16f) > NMS_T));
        }
        u64 avail = __ballot(mv && !hit);

        // build within-chunk adjacency: lane t holds row t
        u64 Rt = 0;
        for (int t = 0; t < chunkn; ++t) {
            int p = (int)wmem[wv][c0 + t];            // LDS broadcast
            float4 bp = sel_sbox[bb + p];             // global broadcast (L1/L2)
            float ap = sel_area[bb + p];
            float ltx = fmaxf(bp.x, bq.x), lty = fmaxf(bp.y, bq.y);
            float rbx = fminf(bp.z, bq.z), rby = fminf(bp.w, bq.w);
            float ww = fmaxf(rbx - ltx, 0.0f), hh = fmaxf(rby - lty, 0.0f);
            float inter = ww * hh;
            u64 row = __ballot(mv && (inter / (ap + aq - inter + 1e-16f) > NMS_T));
            if (lane == t) Rt = row;
        }

        // peel: greedy == lexicographically-first MIS (symmetric adjacency)
        u64 U = avail, kept = 0;
        while (U) {
            bool inU = ((U >> lane) & 1ULL) != 0ULL;
            u64 newk = __ballot(inU && ((Rt & U & below) == 0ULL));
            u64 killed = __ballot((Rt & newk) != 0ULL);
            kept |= newk;
            U &= ~(newk | killed);
        }
        if (lane == 0) wkeep[wv][c0 >> 6] = kept;
        if ((kept >> lane) & 1ULL)
            atomicOr(&gkeep[(size_t)b * NWORD + (q >> 6)], 1ULL << (q & 63));
    }
}

// ---- Kernel 4: compact kept entries (descending-score order) + zero fill ----
__global__ __launch_bounds__(64) void k_out(const u64* __restrict__ gkeep,
                                            const float4* __restrict__ sel_box,
                                            const float* __restrict__ sel_score,
                                            const int* __restrict__ sel_cls,
                                            float* __restrict__ out) {
    int b = blockIdx.x;
    int lane = threadIdx.x;
    const float* SC = sel_score + (size_t)b * NSEL;
    u64 kreg = (lane < NWORD) ? gkeep[(size_t)b * NWORD + lane] : 0ULL;

    int cnt = (lane < NWORD) ? __popcll(kreg) : 0;
    int pre = cnt;
    #pragma unroll
    for (int dd = 1; dd < 64; dd <<= 1) {
        int o = __shfl_up(pre, dd);
        if (lane >= dd) pre += o;
    }
    int total = __shfl(pre, 63);
    int base = pre - cnt;
    float* OUT = out + (size_t)b * MAXDET * 6;
    if (lane < NWORD) {
        u64 m = kreg;
        int rr = 0;
        while (m) {
            int t = __ffsll((long long)m) - 1;
            m &= m - 1;
            int slot = base + rr; ++rr;
            if (slot < MAXDET) {
                int i = lane * 64 + t;
                size_t src = (size_t)b * NSEL + i;
                float4 bx = sel_box[src];
                float sc = SC[i];
                int c = sel_cls[src];
                float* o6 = OUT + slot * 6;
                o6[0] = bx.x; o6[1] = bx.y; o6[2] = bx.z; o6[3] = bx.w;
                o6[4] = sc; o6[5] = (float)c;
            }
        }
    }
    int start = total > MAXDET ? MAXDET : total;
    for (int s = start + lane; s < MAXDET; s += 64) {
        float* o6 = OUT + s * 6;
        o6[0] = 0.0f; o6[1] = 0.0f; o6[2] = 0.0f;
        o6[3] = 0.0f; o6[4] = 0.0f; o6[5] = 0.0f;
    }
}

// ---------------- Launcher ----------------
extern "C" void kernel_launch(void* const* d_in, const int* in_sizes, int n_in,
                              void* d_out, int out_size, void* d_ws, size_t ws_size,
                              hipStream_t stream) {
    const float* pred = (const float*)d_in[0];
    float* out = (float*)d_out;

    char* ws = (char*)d_ws;
    size_t off = 0;
    auto alloc = [&](size_t bytes) -> void* {
        void* p = ws + off;
        off += (bytes + 255) & ~(size_t)255;
        return p;
    };

    u64*    keys      = (u64*)   alloc((size_t)NBATCH * NSORT * 8);
    float4* boxes     = (float4*)alloc((size_t)NBATCH * NANCH * 16);
    int*    cls       = (int*)   alloc((size_t)NBATCH * NANCH * 4);
    float*  score     = (float*) alloc((size_t)NBATCH * NANCH * 4);
    float4* sel_box   = (float4*)alloc((size_t)NBATCH * NSEL * 16);
    float4* sel_sbox  = (float4*)alloc((size_t)NBATCH * NSEL * 16);
    float*  sel_area  = (float*) alloc((size_t)NBATCH * NSEL * 4);
    float*  sel_score = (float*) alloc((size_t)NBATCH * NSEL * 4);
    int*    sel_cls   = (int*)   alloc((size_t)NBATCH * NSEL * 4);
    u64*    gkeep     = (u64*)   alloc((size_t)NBATCH * NWORD * 8);       // 4 KB
    u32*    ghist     = (u32*)   alloc((size_t)NBATCH * 256 * 4);         // 16 KB (contiguous after gkeep)

    // zero gkeep + ghist with a tiny kernel (hipMemsetAsync graph blit was 41 us)
    int zwords = (int)(((size_t)NBATCH * NWORD * 8 + (size_t)NBATCH * 256 * 4) / 4);
    k_zero<<<1, 1024, 0, stream>>>((u32*)gkeep, zwords);

    dim3 g1((NANCH + 127) / 128, NBATCH);
    k_prep<<<g1, 256, 0, stream>>>(pred, keys, boxes, cls, score, ghist);

    k_sel<<<NBATCH, 1024, 0, stream>>>(keys, ghist, boxes, cls, score,
                                       sel_box, sel_sbox, sel_area,
                                       sel_score, sel_cls);

    dim3 g3(5, NBATCH);
    k_cnms<<<g3, 1024, 0, stream>>>(sel_sbox, sel_area, sel_cls, sel_score, gkeep);

    k_out<<<NBATCH, 64, 0, stream>>>(gkeep, sel_box, sel_score, sel_cls, out);
}

// Round 13
// 109.360 us; speedup vs baseline: 1.4934x; 1.4934x over previous
//
#include <hip/hip_runtime.h>
#include <hip/hip_bf16.h>
#include <stdint.h>

typedef unsigned long long u64;
typedef unsigned int u32;
typedef unsigned short u16;

#define NANCH 10647
#define NBATCH 16
#define NSORT 16384
#define NSEL 2048
#define NWORD 32
#define NCLS 80
#define CONF_T 0.5f
#define NMS_T 0.5f
#define MAXDET 300
#define MAXWH 4096.0f
#define CANDCAP 10688   // >= NANCH, 64-aligned

// ---------------- Kernel 0: zero ghist + gkeep ----------------
__global__ __launch_bounds__(1024) void k_zero(u32* __restrict__ p, int nwords) {
    for (int i = threadIdx.x; i < nwords; i += 1024) p[i] = 0;
}

// ---------------- Kernel 1: per-anchor prep (+ top-byte histogram) ----------------
__global__ __launch_bounds__(256) void k_prep(const float* __restrict__ pred,
                                              u64* __restrict__ keys,
                                              float4* __restrict__ boxes,
                                              int* __restrict__ cls,
                                              float* __restrict__ score,
                                              u32* __restrict__ ghist) {
    __shared__ float sm[128 * 85];
    __shared__ u32 ph[256];
    int b = blockIdx.y;
    int a0 = blockIdx.x * 128;
    int na = NANCH - a0; if (na > 128) na = 128;
    const float* src = pred + ((size_t)b * NANCH + a0) * 85;
    int tot = na * 85;
    ph[threadIdx.x] = 0;
    for (int i = threadIdx.x; i < tot; i += 256) sm[i] = src[i];
    __syncthreads();
    int t = threadIdx.x;
    u64 kk = 0;
    if (t < na) {
        const float* s = &sm[t * 85];
        float x = s[0], y = s[1], w = s[2], h = s[3], obj = s[4];
        float best = s[5] * obj; int arg = 0;
        #pragma unroll
        for (int c = 1; c < 80; ++c) {
            float v = s[5 + c] * obj;
            if (v > best) { best = v; arg = c; }
        }
        bool valid = obj >= CONF_T;
        float sc = valid ? best : -1.0f;
        int a = a0 + t;
        float4 bx;
        bx.x = x - w * 0.5f; bx.y = y - h * 0.5f;
        bx.z = x + w * 0.5f; bx.w = y + h * 0.5f;
        size_t o = (size_t)b * NANCH + a;
        boxes[o] = bx;
        cls[o] = arg;
        score[o] = sc;
        u32 u = __float_as_uint(sc);
        u32 v = (u & 0x80000000u) ? ~u : (u | 0x80000000u); // ascending map
        u32 hi = ~v;                                        // descending
        kk = ((u64)hi << 32) | (u32)a;
        keys[(size_t)b * NSORT + a] = kk;
    }
    // wave-aggregated 256-bin histogram of key top byte
    u32 bin = (t < na) ? (u32)(kk >> 56) : 0xFFFFFFFFu;
    int lane = t & 63;
    u64 rem = __ballot(t < na);
    while (rem) {
        int srcl = __ffsll((long long)rem) - 1;
        u32 lb = __shfl(bin, srcl);
        u64 same = __ballot(bin == lb) & rem;
        if (lane == srcl) atomicAdd(&ph[lb], (u32)__popcll(same));
        rem &= ~same;
    }
    __syncthreads();
    if (ph[threadIdx.x]) atomicAdd(&ghist[(size_t)b * 256 + threadIdx.x], ph[threadIdx.x]);
}

// ------- Kernel 2: histogram-seeded select + hybrid bitonic + gather -------
// Invariant through selection: s_cnt + s_rank == NSEL at every loop entry.
__global__ __launch_bounds__(1024) void k_sel(const u64* __restrict__ keys,
                                              const u32* __restrict__ ghist,
                                              const float4* __restrict__ boxes,
                                              const int* __restrict__ cls,
                                              const float* __restrict__ score,
                                              float4* __restrict__ sel_box,
                                              float4* __restrict__ sel_sbox,
                                              float* __restrict__ sel_area,
                                              float* __restrict__ sel_score,
                                              int* __restrict__ sel_cls) {
    __shared__ u64 sk[NSEL];        // 16 KB
    __shared__ u64 cand[CANDCAP];   // 85.5 KB
    __shared__ u32 hist[256];
    __shared__ u32 hsc[256];
    __shared__ u64 s_red[16];
    __shared__ u32 s_D0, s_D, s_rank, s_cnt, s_cand;

    int b = blockIdx.x;
    int tid = threadIdx.x;
    int lane = tid & 63;
    u64 below = (1ULL << lane) - 1ULL;
    const u64* KB = keys + (size_t)b * NSORT;

    if (tid == 0) { s_cnt = 0; s_cand = 0; }
    for (int i = tid; i < NSEL; i += 1024) sk[i] = ~0ULL;   // safety fill
    // ---- round 0: digit from precomputed histogram ----
    if (tid < 256) hist[tid] = ghist[(size_t)b * 256 + tid];
    __syncthreads();
    if (tid < 64) {
        u32 h0 = hist[tid*4], h1 = hist[tid*4+1], h2 = hist[tid*4+2], h3 = hist[tid*4+3];
        u32 loc = h0 + h1 + h2 + h3;
        u32 p = loc;
        #pragma unroll
        for (int o = 1; o < 64; o <<= 1) { u32 t2 = __shfl_up(p, o); if (lane >= o) p += t2; }
        u32 base = p - loc;
        hsc[tid*4]   = base + h0;
        hsc[tid*4+1] = base + h0 + h1;
        hsc[tid*4+2] = base + h0 + h1 + h2;
        hsc[tid*4+3] = base + h0 + h1 + h2 + h3;
    }
    __syncthreads();
    if (tid < 256) {
        u32 inc = hsc[tid], cb = inc - hist[tid];
        if (cb < NSEL && NSEL <= inc) { s_D0 = tid; s_rank = NSEL - cb; }
    }
    __syncthreads();
    u32 D0 = s_D0;

    // ---- single fused scan: sure-set -> sk, boundary bucket -> cand ----
    for (int it = 0; it < 11; ++it) {
        int i = tid + it * 1024;
        bool inb = i < NANCH;
        u64 kk = inb ? KB[i] : 0ULL;
        u32 top = (u32)(kk >> 56);
        bool is_s = inb && (top < D0);
        bool is_c = inb && (top == D0);
        u64 bs = __ballot(is_s), bc = __ballot(is_c);
        u32 base_s = 0, base_c = 0;
        if (lane == 0) {
            if (bs) base_s = atomicAdd(&s_cnt, (u32)__popcll(bs));
            if (bc) base_c = atomicAdd(&s_cand, (u32)__popcll(bc));
        }
        base_s = __shfl(base_s, 0); base_c = __shfl(base_c, 0);
        if (is_s) sk[base_s + __popcll(bs & below)] = kk;
        if (is_c) cand[base_c + __popcll(bc & below)] = kk;
    }
    __syncthreads();

    // ---- refine within cand; append sure-members to sk each round ----
    const int shifts2[5] = {48, 40, 32, 8, 0};
    for (int rr = 0; ; ++rr) {
        u32 cn = s_cand, r = s_rank;
        if (r == cn || rr == 5) {
            for (u32 i0 = 0; i0 < cn; i0 += 1024) {
                u32 i = i0 + tid;
                bool take = i < cn;
                u64 kk = take ? cand[i] : 0ULL;
                u64 bt = __ballot(take);
                u32 base = 0;
                if (lane == 0 && bt) base = atomicAdd(&s_cnt, (u32)__popcll(bt));
                base = __shfl(base, 0);
                if (take) sk[base + __popcll(bt & below)] = kk;
            }
            break;
        }
        if (r == 1) {
            u64 best = ~0ULL;
            for (u32 i = tid; i < cn; i += 1024) { u64 kk = cand[i]; if (kk < best) best = kk; }
            #pragma unroll
            for (int o = 32; o > 0; o >>= 1) {
                u64 other = __shfl_down(best, o);
                if (other < best) best = other;
            }
            if (lane == 0) s_red[tid >> 6] = best;
            __syncthreads();
            if (tid == 0) {
                u64 m = s_red[0];
                for (int w2 = 1; w2 < 16; ++w2) if (s_red[w2] < m) m = s_red[w2];
                sk[atomicAdd(&s_cnt, 1u)] = m;
            }
            break;
        }
        int shift = shifts2[rr];
        if (tid < 256) hist[tid] = 0;
        __syncthreads();
        for (u32 i = tid; i < cn; i += 1024)
            atomicAdd(&hist[(u32)(cand[i] >> shift) & 0xFFu], 1u);
        __syncthreads();
        if (tid < 64) {
            u32 h0 = hist[tid*4], h1 = hist[tid*4+1], h2 = hist[tid*4+2], h3 = hist[tid*4+3];
            u32 loc = h0 + h1 + h2 + h3;
            u32 p = loc;
            #pragma unroll
            for (int o = 1; o < 64; o <<= 1) { u32 t2 = __shfl_up(p, o); if (lane >= o) p += t2; }
            u32 base = p - loc;
            hsc[tid*4]   = base + h0;
            hsc[tid*4+1] = base + h0 + h1;
            hsc[tid*4+2] = base + h0 + h1 + h2;
            hsc[tid*4+3] = base + h0 + h1 + h2 + h3;
        }
        __syncthreads();
        if (tid < 256) {
            u32 inc = hsc[tid], cb = inc - hist[tid];
            if (cb < r && r <= inc) { s_D = tid; s_rank = r - cb; }
        }
        __syncthreads();
        u32 D = s_D;
        // partition: digit<D -> sk (sure members), digit==D -> cand, else drop
        u64 mk[11], mc[11]; int nk = 0, nc = 0;
        for (u32 i = tid; i < cn; i += 1024) {
            u64 kk = cand[i];
            u32 dg = (u32)(kk >> shift) & 0xFFu;
            if (dg < D) mk[nk++] = kk;
            else if (dg == D) mc[nc++] = kk;
        }
        __syncthreads();
        if (tid == 0) s_cand = 0;
        __syncthreads();
        if (nk) { u32 p = atomicAdd(&s_cnt, (u32)nk); for (int j = 0; j < nk; ++j) sk[p + j] = mk[j]; }
        if (nc) { u32 p = atomicAdd(&s_cand, (u32)nc); for (int j = 0; j < nc; ++j) cand[p + j] = mc[j]; }
        __syncthreads();
    }
    __syncthreads();

    // ---- hybrid bitonic sort 2048 keys ascending ----
    // Wave w owns contiguous 128 elements; reg a = idx base+l, reg c = base+64+l.
    // j<=32: shfl_xor CE; j==64: in-thread reg CE; j>=128: LDS CE stages.
    {
        int w = tid >> 6, l = lane;
        int base = w * 128;
        u64 a = sk[base + l], c = sk[base + 64 + l];
        // k = 2..128 entirely in registers (directions from true global index)
        #pragma unroll
        for (int k = 2; k <= 128; k <<= 1) {
            for (int j = k >> 1; j > 0; j >>= 1) {
                if (j == 64) {
                    bool dir = (((base + l) & k) == 0);
                    u64 lo = a < c ? a : c;
                    u64 hi = a < c ? c : a;
                    a = dir ? lo : hi;
                    c = dir ? hi : lo;
                } else {
                    bool up_ = (l & j) != 0;
                    bool dira = (((base + l) & k) == 0);
                    bool dirc = (((base + 64 + l) & k) == 0);
                    u64 pa = __shfl_xor(a, j);
                    u64 pc = __shfl_xor(c, j);
                    a = (up_ == dira) ? (a > pa ? a : pa) : (a < pa ? a : pa);
                    c = (up_ == dirc) ? (c > pc ? c : pc) : (c < pc ? c : pc);
                }
            }
        }
        sk[base + l] = a; sk[base + 64 + l] = c;
        __syncthreads();
        // k = 256..2048: LDS stages for j>=128, register tail for j<=64
        for (int k = 256; k <= NSEL; k <<= 1) {
            for (int j = k >> 1; j >= 128; j >>= 1) {
                int n = tid;
                int i = ((n & ~(j - 1)) << 1) | (n & (j - 1));
                int l2 = i | j;
                u64 x = sk[i], y = sk[l2];
                bool up2 = ((i & k) == 0);
                if ((x > y) == up2) { sk[i] = y; sk[l2] = x; }
                __syncthreads();
            }
            a = sk[base + l]; c = sk[base + 64 + l];
            bool dirk = ((base & k) == 0);   // uniform within the 128-block
            {
                u64 lo = a < c ? a : c;
                u64 hi = a < c ? c : a;
                a = dirk ? lo : hi;
                c = dirk ? hi : lo;
            }
            #pragma unroll
            for (int j = 32; j > 0; j >>= 1) {
                bool up_ = (l & j) != 0;
                u64 pa = __shfl_xor(a, j);
                u64 pc = __shfl_xor(c, j);
                a = (up_ == dirk) ? (a > pa ? a : pa) : (a < pa ? a : pa);
                c = (up_ == dirk) ? (c > pc ? c : pc) : (c < pc ? c : pc);
            }
            sk[base + l] = a; sk[base + 64 + l] = c;
            __syncthreads();
        }
    }

    // ---- gather selected entries (clamped index: fault-safe) ----
    for (int r2 = tid; r2 < NSEL; r2 += 1024) {
        u64 key = sk[r2];
        int a = (int)(key & 0xFFFFFFFFu);
        if ((unsigned)a >= NANCH) a = 0;   // should never trigger
        size_t src = (size_t)b * NANCH + a;
        float4 bx = boxes[src];
        int c = cls[src];
        float sc = score[src];
        float off = (float)c * MAXWH;
        float4 sb;
        sb.x = bx.x + off; sb.y = bx.y + off;
        sb.z = bx.z + off; sb.w = bx.w + off;
        float area = (sb.z - sb.x) * (sb.w - sb.y);
        size_t o = (size_t)b * NSEL + r2;
        sel_box[o] = bx; sel_sbox[o] = sb; sel_area[o] = area;
        sel_score[o] = sc; sel_cls[o] = c;
    }
}

// ---- Kernel 3: per-class NMS (IoU matrix is block-diagonal by class) ----
__global__ __launch_bounds__(1024) void k_cnms(const float4* __restrict__ sel_sbox,
                                               const float* __restrict__ sel_area,
                                               const int* __restrict__ sel_cls,
                                               const float* __restrict__ sel_score,
                                               u64* __restrict__ gkeep) {
    __shared__ u16 wmem[16][NSEL];    // 64 KB: per-wave member list
    __shared__ u64 wkeep[16][NWORD];  // 4 KB: per-wave kept bits

    int b = blockIdx.y;
    int cg = blockIdx.x;              // class group 0..4
    int lane = threadIdx.x & 63, wv = threadIdx.x >> 6;
    int c = cg * 16 + wv;             // this wave's class, 0..79
    size_t bb = (size_t)b * NSEL;
    const int* CL = sel_cls + bb;
    const float* SC = sel_score + bb;
    u64 below = (1ULL << lane) - 1ULL;

    // ---- build member list (ascending selected index == descending score) ----
    int n = 0;
    for (int ch = 0; ch < NWORD; ++ch) {
        int i = ch * 64 + lane;
        bool pred = (CL[i] == c) && (SC[i] >= 0.0f);
        u64 bal = __ballot(pred);
        if (pred) wmem[wv][n + __popcll(bal & below)] = (u16)i;
        n += __popcll(bal);
    }

    // ---- greedy NMS over this class's members, 64 at a time ----
    for (int c0 = 0; c0 < n; c0 += 64) {
        int chunkn = n - c0; if (chunkn > 64) chunkn = 64;
        bool mv = lane < chunkn;
        int q = mv ? (int)wmem[wv][c0 + lane] : 0;
        float4 bq = sel_sbox[bb + q];
        float aq = sel_area[bb + q];

        // hit-test vs earlier kept members (only runs when n > 64)
        bool hit = false;
        for (int j = 0; j < c0; ++j) {
            if (!((wkeep[wv][j >> 6] >> (j & 63)) & 1ULL)) continue;
            int p = (int)wmem[wv][j];
            float4 bp = sel_sbox[bb + p];
            float ap = sel_area[bb + p];
            float ltx = fmaxf(bp.x, bq.x), lty = fmaxf(bp.y, bq.y);
            float rbx = fminf(bp.z, bq.z), rby = fminf(bp.w, bq.w);
            float ww = fmaxf(rbx - ltx, 0.0f), hh = fmaxf(rby - lty, 0.0f);
            float inter = ww * hh;
            hit = hit || (mv && (inter / (ap + aq - inter + 1e-16f) > NMS_T));
        }
        u64 avail = __ballot(mv && !hit);

        // build within-chunk adjacency: lane t holds row t
        u64 Rt = 0;
        for (int t = 0; t < chunkn; ++t) {
            int p = (int)wmem[wv][c0 + t];            // LDS broadcast
            float4 bp = sel_sbox[bb + p];             // global broadcast (L1/L2)
            float ap = sel_area[bb + p];
            float ltx = fmaxf(bp.x, bq.x), lty = fmaxf(bp.y, bq.y);
            float rbx = fminf(bp.z, bq.z), rby = fminf(bp.w, bq.w);
            float ww = fmaxf(rbx - ltx, 0.0f), hh = fmaxf(rby - lty, 0.0f);
            float inter = ww * hh;
            u64 row = __ballot(mv && (inter / (ap + aq - inter + 1e-16f) > NMS_T));
            if (lane == t) Rt = row;
        }

        // peel: greedy == lexicographically-first MIS (symmetric adjacency)
        u64 U = avail, kept = 0;
        while (U) {
            bool inU = ((U >> lane) & 1ULL) != 0ULL;
            u64 newk = __ballot(inU && ((Rt & U & below) == 0ULL));
            u64 killed = __ballot((Rt & newk) != 0ULL);
            kept |= newk;
            U &= ~(newk | killed);
        }
        if (lane == 0) wkeep[wv][c0 >> 6] = kept;
        if ((kept >> lane) & 1ULL)
            atomicOr(&gkeep[(size_t)b * NWORD + (q >> 6)], 1ULL << (q & 63));
    }
}

// ---- Kernel 4: compact kept entries (descending-score order) + zero fill ----
__global__ __launch_bounds__(64) void k_out(const u64* __restrict__ gkeep,
                                            const float4* __restrict__ sel_box,
                                            const float* __restrict__ sel_score,
                                            const int* __restrict__ sel_cls,
                                            float* __restrict__ out) {
    int b = blockIdx.x;
    int lane = threadIdx.x;
    const float* SC = sel_score + (size_t)b * NSEL;
    u64 kreg = (lane < NWORD) ? gkeep[(size_t)b * NWORD + lane] : 0ULL;

    int cnt = (lane < NWORD) ? __popcll(kreg) : 0;
    int pre = cnt;
    #pragma unroll
    for (int dd = 1; dd < 64; dd <<= 1) {
        int o = __shfl_up(pre, dd);
        if (lane >= dd) pre += o;
    }
    int total = __shfl(pre, 63);
    int base = pre - cnt;
    float* OUT = out + (size_t)b * MAXDET * 6;
    if (lane < NWORD) {
        u64 m = kreg;
        int rr = 0;
        while (m) {
            int t = __ffsll((long long)m) - 1;
            m &= m - 1;
            int slot = base + rr; ++rr;
            if (slot < MAXDET) {
                int i = lane * 64 + t;
                size_t src = (size_t)b * NSEL + i;
                float4 bx = sel_box[src];
                float sc = SC[i];
                int c = sel_cls[src];
                float* o6 = OUT + slot * 6;
                o6[0] = bx.x; o6[1] = bx.y; o6[2] = bx.z; o6[3] = bx.w;
                o6[4] = sc; o6[5] = (float)c;
            }
        }
    }
    int start = total > MAXDET ? MAXDET : total;
    for (int s = start + lane; s < MAXDET; s += 64) {
        float* o6 = OUT + s * 6;
        o6[0] = 0.0f; o6[1] = 0.0f; o6[2] = 0.0f;
        o6[3] = 0.0f; o6[4] = 0.0f; o6[5] = 0.0f;
    }
}

// ---------------- Launcher ----------------
extern "C" void kernel_launch(void* const* d_in, const int* in_sizes, int n_in,
                              void* d_out, int out_size, void* d_ws, size_t ws_size,
                              hipStream_t stream) {
    const float* pred = (const float*)d_in[0];
    float* out = (float*)d_out;

    char* ws = (char*)d_ws;
    size_t off = 0;
    auto alloc = [&](size_t bytes) -> void* {
        void* p = ws + off;
        off += (bytes + 255) & ~(size_t)255;
        return p;
    };

    u64*    keys      = (u64*)   alloc((size_t)NBATCH * NSORT * 8);
    float4* boxes     = (float4*)alloc((size_t)NBATCH * NANCH * 16);
    int*    cls       = (int*)   alloc((size_t)NBATCH * NANCH * 4);
    float*  score     = (float*) alloc((size_t)NBATCH * NANCH * 4);
    float4* sel_box   = (float4*)alloc((size_t)NBATCH * NSEL * 16);
    float4* sel_sbox  = (float4*)alloc((size_t)NBATCH * NSEL * 16);
    float*  sel_area  = (float*) alloc((size_t)NBATCH * NSEL * 4);
    float*  sel_score = (float*) alloc((size_t)NBATCH * NSEL * 4);
    int*    sel_cls   = (int*)   alloc((size_t)NBATCH * NSEL * 4);
    u64*    gkeep     = (u64*)   alloc((size_t)NBATCH * NWORD * 8);       // 4 KB
    u32*    ghist     = (u32*)   alloc((size_t)NBATCH * 256 * 4);         // 16 KB (contiguous after gkeep)

    // zero gkeep + ghist with a tiny kernel (hipMemsetAsync graph blit was 41 us)
    int zwords = (int)(((size_t)NBATCH * NWORD * 8 + (size_t)NBATCH * 256 * 4) / 4);
    k_zero<<<1, 1024, 0, stream>>>((u32*)gkeep, zwords);

    dim3 g1((NANCH + 127) / 128, NBATCH);
    k_prep<<<g1, 256, 0, stream>>>(pred, keys, boxes, cls, score, ghist);

    k_sel<<<NBATCH, 1024, 0, stream>>>(keys, ghist, boxes, cls, score,
                                       sel_box, sel_sbox, sel_area,
                                       sel_score, sel_cls);

    dim3 g3(5, NBATCH);
    k_cnms<<<g3, 1024, 0, stream>>>(sel_sbox, sel_area, sel_cls, sel_score, gkeep);

    k_out<<<NBATCH, 64, 0, stream>>>(gkeep, sel_box, sel_score, sel_cls, out);
}